// Round 1
// baseline (10407.841 us; speedup 1.0000x reference)
//
#include <hip/hip_runtime.h>
#include <hip/hip_bf16.h>
#include <float.h>
#include <math.h>

#define B_ 64
#define S_ 256
#define E_ 300
#define H_ 512
#define T_ 10

// ---- workspace layout (f32 element offsets) ----
// x:      [S][B][E]       gathered embeddings
// hbuf:   [2][2][B][H]    (parity, dir, b, j)  carried hidden state
// cbuf:   [2][B][H]       (dir, b, j)          cell state
// houts:  [S][B][2H]      masked hidden outputs, [hf | hb] per (s,b)
// feats:  [B][S][T]       emission scores
#define X_OFF     0
#define X_SZ      (S_*B_*E_)
#define HBUF_OFF  (X_OFF + X_SZ)
#define HBUF_SZ   (2*2*B_*H_)
#define CBUF_OFF  (HBUF_OFF + HBUF_SZ)
#define CBUF_SZ   (2*B_*H_)
#define HOUT_OFF  (CBUF_OFF + CBUF_SZ)
#define HOUT_SZ   (S_*B_*2*H_)
#define FEAT_OFF  (HOUT_OFF + HOUT_SZ)
#define FEAT_SZ   (B_*S_*T_)

// -------------------- embedding gather: x[s][b][e] = emb[tok[b][s]][e] --------------------
__global__ void k_gather(const int* __restrict__ tok, const float* __restrict__ emb,
                         float* __restrict__ x) {
    const long long total = (long long)S_ * B_ * E_;
    for (long long i = (long long)blockIdx.x * blockDim.x + threadIdx.x; i < total;
         i += (long long)gridDim.x * blockDim.x) {
        int e  = (int)(i % E_);
        int sb = (int)(i / E_);
        int b = sb & 63;
        int s = sb >> 6;
        x[i] = emb[(long long)tok[b * S_ + s] * E_ + e];
    }
}

// -------------------- one LSTM time step (both directions) --------------------
// grid 256 = (d:2) x (jb:32) x (bb:4); block 256 = (gate-row r:64) x (k-quarter kq:4)
__global__ __launch_bounds__(256) void k_step(
    const float* __restrict__ wih_f, const float* __restrict__ whh_f, const float* __restrict__ b_f,
    const float* __restrict__ wih_b, const float* __restrict__ whh_b, const float* __restrict__ b_b,
    const int* __restrict__ lengths, float* __restrict__ ws, int sIdx) {

    const int bi = blockIdx.x;
    const int d  = bi & 1;
    const int jb = (bi >> 1) & 31;   // j-block of 16 hidden units
    const int bb = bi >> 6;          // batch block of 16
    const int tid = threadIdx.x;
    const int r  = tid & 63;         // gate row within block: jg_local = j_local*4 + t
    const int kq = tid >> 6;         // k-quarter 0..3

    const int s = d ? (S_ - 1 - sIdx) : sIdx;
    const int p = sIdx & 1;          // parity of hidden double-buffer

    const int j_local = r >> 2, t = r & 3;
    const int jj = jb * 16 + j_local;       // hidden index 0..511
    const int g  = t * H_ + jj;             // gate row in [4H]

    const float* wih  = d ? wih_b : wih_f;
    const float* whh  = d ? whh_b : whh_f;
    const float* bias = d ? b_b  : b_f;

    const float* x     = ws + X_OFF;
    float* hbuf  = ws + HBUF_OFF;
    float* cbuf  = ws + CBUF_OFF;
    float* houts = ws + HOUT_OFF;

    // previous hidden state for this (d, batch-block)
    const float* hprev = hbuf + ((size_t)(p * 2 + d) * B_ + bb * 16) * H_;
    const float* wh_row = whh + (size_t)g * H_ + kq * 128;
    const float* wx_row = wih + (size_t)g * E_;
    const int xoff = kq * 76;                 // 76,76,76,72 split of E=300 (16B aligned)
    const int xlen = (kq == 3) ? 72 : 76;

    float acc[16];
#pragma unroll
    for (int b = 0; b < 16; b++) acc[b] = 0.f;

    // recurrent part: k in [kq*128, kq*128+128)
    for (int k0 = 0; k0 < 128; k0 += 4) {
        float4 w4 = *reinterpret_cast<const float4*>(wh_row + k0);
#pragma unroll
        for (int b = 0; b < 16; b++) {
            float4 h4 = *reinterpret_cast<const float4*>(hprev + (size_t)b * H_ + kq * 128 + k0);
            acc[b] += w4.x * h4.x + w4.y * h4.y + w4.z * h4.z + w4.w * h4.w;
        }
    }
    // input part: e in [xoff, xoff+xlen)
    for (int e0 = 0; e0 < xlen; e0 += 4) {
        float4 w4 = *reinterpret_cast<const float4*>(wx_row + xoff + e0);
#pragma unroll
        for (int b = 0; b < 16; b++) {
            float4 x4 = *reinterpret_cast<const float4*>(
                x + ((size_t)s * B_ + bb * 16 + b) * E_ + xoff + e0);
            acc[b] += w4.x * x4.x + w4.y * x4.y + w4.z * x4.z + w4.w * x4.w;
        }
    }

    __shared__ float part[4][64][16];
#pragma unroll
    for (int b = 0; b < 16; b++) part[kq][r][b] = acc[b];
    __syncthreads();

    // reduce phase: thread = (j_local2: 16) x (b2: 16)
    const int jl2 = tid >> 4;
    const int b2  = tid & 15;
    float gs[4];
#pragma unroll
    for (int tt = 0; tt < 4; tt++) {
        int rr = jl2 * 4 + tt;
        gs[tt] = part[0][rr][b2] + part[1][rr][b2] + part[2][rr][b2] + part[3][rr][b2];
    }
    const int jj2 = jb * 16 + jl2;
#pragma unroll
    for (int tt = 0; tt < 4; tt++) gs[tt] += bias[tt * H_ + jj2];

    const int bg  = bb * 16 + b2;
    const int len = lengths[bg];
    const bool m  = (s < len);

    float iG = 1.f / (1.f + expf(-gs[0]));
    float fG = 1.f / (1.f + expf(-gs[1]));
    float gG = tanhf(gs[2]);
    float oG = 1.f / (1.f + expf(-gs[3]));

    float* cp = cbuf + ((size_t)d * B_ + bg) * H_ + jj2;
    float c_old = *cp;
    float c_new = fG * c_old + iG * gG;
    float h_new = oG * tanhf(c_new);
    float h_old = hbuf[((size_t)(p * 2 + d) * B_ + bg) * H_ + jj2];

    *cp = m ? c_new : c_old;
    hbuf[((size_t)((p ^ 1) * 2 + d) * B_ + bg) * H_ + jj2] = m ? h_new : h_old;
    houts[((size_t)s * B_ + bg) * (2 * H_) + d * H_ + jj2] = m ? h_new : 0.f;
}

// -------------------- output projection: feats[b][s][t] --------------------
// grid 256 (per s); block 640 = 10 waves (t) x 64 lanes (b)
__global__ __launch_bounds__(640) void k_feats(const float* __restrict__ w_out,
                                               const float* __restrict__ b_out,
                                               float* __restrict__ ws) {
    const int s = blockIdx.x;
    const int t = threadIdx.x >> 6;   // 0..9
    const int b = threadIdx.x & 63;
    const float* houts = ws + HOUT_OFF;
    float* feats = ws + FEAT_OFF;
    const float* hrow = houts + ((size_t)s * B_ + b) * (2 * H_);
    const float* wrow = w_out + (size_t)t * (2 * H_);
    float acc = b_out[t];
    for (int j = 0; j < 2 * H_; j += 4) {
        float4 h4 = *reinterpret_cast<const float4*>(hrow + j);
        float4 w4 = *reinterpret_cast<const float4*>(wrow + j);
        acc += h4.x * w4.x + h4.y * w4.y + h4.z * w4.z + h4.w * w4.w;
    }
    feats[((size_t)b * S_ + s) * T_ + t] = acc;
}

// -------------------- Viterbi decode (one wave per batch row) --------------------
__global__ __launch_bounds__(64) void k_viterbi(const float* __restrict__ start_t,
                                                const float* __restrict__ end_t,
                                                const float* __restrict__ trans,
                                                const int* __restrict__ lengths,
                                                const float* __restrict__ ws,
                                                int* __restrict__ out) {
    const int b = blockIdx.x;
    const int lane = threadIdx.x;
    const int tt = (lane < T_) ? lane : 0;
    const float* feats = ws + FEAT_OFF;
    __shared__ unsigned char bpl[S_][T_];

    float tr[T_];
#pragma unroll
    for (int i = 0; i < T_; i++) tr[i] = trans[i * T_ + tt];   // column tt

    const int len = lengths[b];
    const float* fb = feats + (size_t)b * S_ * T_;
    float score = start_t[tt] + fb[tt];

    for (int s = 1; s < S_; s++) {
        float em = fb[s * T_ + tt];
        float best = -FLT_MAX;
        int bi = 0;
#pragma unroll
        for (int i = 0; i < T_; i++) {
            float si = __shfl(score, i);
            float c = si + tr[i];
            if (c > best) { best = c; bi = i; }   // strict > : first-max like argmax
        }
        bool m = (s < len);
        score = m ? (best + em) : score;
        if (lane < T_) bpl[s][lane] = (unsigned char)(m ? bi : lane);
    }

    float tot = score + end_t[tt];
    float best = -FLT_MAX;
    int last = 0;
#pragma unroll
    for (int i = 0; i < T_; i++) {
        float v = __shfl(tot, i);
        if (v > best) { best = v; last = i; }
    }
    __syncthreads();
    if (lane == 0) {
        int tag = last;
        out[b * S_ + (S_ - 1)] = ((S_ - 1) < len) ? tag : 0;
        for (int s = S_ - 2; s >= 0; s--) {
            tag = bpl[s + 1][tag];
            out[b * S_ + s] = (s < len) ? tag : 0;
        }
    }
}

// -------------------- launcher --------------------
extern "C" void kernel_launch(void* const* d_in, const int* in_sizes, int n_in,
                              void* d_out, int out_size, void* d_ws, size_t ws_size,
                              hipStream_t stream) {
    const int*   tok   = (const int*)  d_in[0];
    const int*   len   = (const int*)  d_in[1];
    const float* emb   = (const float*)d_in[2];
    const float* wih_f = (const float*)d_in[3];
    const float* whh_f = (const float*)d_in[4];
    const float* b_f   = (const float*)d_in[5];
    const float* wih_b = (const float*)d_in[6];
    const float* whh_b = (const float*)d_in[7];
    const float* b_b   = (const float*)d_in[8];
    const float* w_out = (const float*)d_in[9];
    const float* b_out = (const float*)d_in[10];
    const float* st    = (const float*)d_in[11];
    const float* en    = (const float*)d_in[12];
    const float* tr    = (const float*)d_in[13];

    float* ws = (float*)d_ws;
    int* out = (int*)d_out;

    // zero the carried state (ws is poisoned 0xAA before every timed launch)
    hipMemsetAsync(ws + HBUF_OFF, 0, (size_t)(HBUF_SZ + CBUF_SZ) * sizeof(float), stream);

    k_gather<<<2400, 256, 0, stream>>>(tok, emb, ws + X_OFF);

    for (int sIdx = 0; sIdx < S_; sIdx++) {
        k_step<<<256, 256, 0, stream>>>(wih_f, whh_f, b_f, wih_b, whh_b, b_b, len, ws, sIdx);
    }

    k_feats<<<256, 640, 0, stream>>>(w_out, b_out, ws);
    k_viterbi<<<64, 64, 0, stream>>>(st, en, tr, len, ws, out);
}

// Round 2
// 7360.165 us; speedup vs baseline: 1.4141x; 1.4141x over previous
//
#include <hip/hip_runtime.h>
#include <hip/hip_bf16.h>
#include <float.h>
#include <math.h>

#define B_ 64
#define S_ 256
#define E_ 300
#define H_ 512
#define T_ 10

// ---- workspace layout (f32 element offsets) ----
// x:      [S][E][B]          gathered embeddings, batch-fastest (coalesced)
// hbuf:   [2][2][H][B]       (parity, dir, j, b)  carried hidden state
// cbuf:   [2][H][B]          (dir, j, b)          cell state
// houts:  [S][2][H][B]       masked hidden outputs (0 where masked)
// feats:  [B][S][T]          emission scores
#define X_OFF     0
#define X_SZ      (S_*E_*B_)
#define HBUF_OFF  (X_OFF + X_SZ)
#define HBUF_SZ   (2*2*H_*B_)
#define CBUF_OFF  (HBUF_OFF + HBUF_SZ)
#define CBUF_SZ   (2*H_*B_)
#define HOUT_OFF  (CBUF_OFF + CBUF_SZ)
#define HOUT_SZ   (S_*2*H_*B_)
#define FEAT_OFF  (HOUT_OFF + HOUT_SZ)
#define FEAT_SZ   (B_*S_*T_)

__device__ __forceinline__ float sigm(float v) { return 1.f / (1.f + expf(-v)); }

// -------------------- embedding gather: x[s][e][b] = emb[tok[b][s]][e] --------------------
__global__ void k_gather(const int* __restrict__ tok, const float* __restrict__ emb,
                         float* __restrict__ x) {
    const long long total = (long long)S_ * E_ * B_;
    for (long long i = (long long)blockIdx.x * blockDim.x + threadIdx.x; i < total;
         i += (long long)gridDim.x * blockDim.x) {
        int b    = (int)(i & 63);
        int rest = (int)(i >> 6);
        int e = rest % E_;
        int s = rest / E_;
        x[i] = emb[(long long)tok[b * S_ + s] * E_ + e];
    }
}

// -------------------- one LSTM time step (both directions) --------------------
// grid 256 = (d:2) x (jb:128 blocks of 4 hidden units); block 256 = 4 waves x 64 lanes
// wave w owns hidden unit j = jb*4+w (all four gates); lane = batch b.
__global__ __launch_bounds__(256) void k_step(
    const float* __restrict__ wih_f, const float* __restrict__ whh_f, const float* __restrict__ b_f,
    const float* __restrict__ wih_b, const float* __restrict__ whh_b, const float* __restrict__ b_b,
    const int* __restrict__ lengths, float* __restrict__ ws, int sIdx) {

    const int d  = blockIdx.x >> 7;
    const int jb = blockIdx.x & 127;
    const int w  = threadIdx.x >> 6;
    const int b  = threadIdx.x & 63;
    // force j into an SGPR so weight reads become s_load (wave-uniform)
    const int j  = __builtin_amdgcn_readfirstlane(jb * 4 + w);

    const int s = d ? (S_ - 1 - sIdx) : sIdx;
    const int p = sIdx & 1;

    const float* wih  = d ? wih_b : wih_f;
    const float* whh  = d ? whh_b : whh_f;
    const float* bias = d ? b_b  : b_f;

    const float* hprev = ws + HBUF_OFF + ((size_t)(p * 2 + d) * H_) * B_;
    const float* xs    = ws + X_OFF + (size_t)s * E_ * B_;

    const float* w0 = whh + (size_t)(0 * H_ + j) * H_;
    const float* w1 = whh + (size_t)(1 * H_ + j) * H_;
    const float* w2 = whh + (size_t)(2 * H_ + j) * H_;
    const float* w3 = whh + (size_t)(3 * H_ + j) * H_;

    float a0 = 0.f, a1 = 0.f, a2 = 0.f, a3 = 0.f;

    // recurrent part: k over H, h load coalesced (lane=b), weights scalar
    for (int k0 = 0; k0 < H_; k0 += 8) {
        float hv[8];
#pragma unroll
        for (int u = 0; u < 8; u++) hv[u] = hprev[(k0 + u) * B_ + b];
#pragma unroll
        for (int u = 0; u < 8; u++) {
            a0 += w0[k0 + u] * hv[u];
            a1 += w1[k0 + u] * hv[u];
            a2 += w2[k0 + u] * hv[u];
            a3 += w3[k0 + u] * hv[u];
        }
    }

    const float* v0 = wih + (size_t)(0 * H_ + j) * E_;
    const float* v1 = wih + (size_t)(1 * H_ + j) * E_;
    const float* v2 = wih + (size_t)(2 * H_ + j) * E_;
    const float* v3 = wih + (size_t)(3 * H_ + j) * E_;

    // input part: e over E=300 (fold-in; xw never materialized)
    for (int e0 = 0; e0 < E_; e0 += 4) {
        float xv[4];
#pragma unroll
        for (int u = 0; u < 4; u++) xv[u] = xs[(e0 + u) * B_ + b];
#pragma unroll
        for (int u = 0; u < 4; u++) {
            a0 += v0[e0 + u] * xv[u];
            a1 += v1[e0 + u] * xv[u];
            a2 += v2[e0 + u] * xv[u];
            a3 += v3[e0 + u] * xv[u];
        }
    }

    const float g0 = a0 + bias[0 * H_ + j];
    const float g1 = a1 + bias[1 * H_ + j];
    const float g2 = a2 + bias[2 * H_ + j];
    const float g3 = a3 + bias[3 * H_ + j];

    const int  len = lengths[b];
    const bool m   = (s < len);

    const float iG = sigm(g0);
    const float fG = sigm(g1);
    const float gG = tanhf(g2);
    const float oG = sigm(g3);

    float* cp = ws + CBUF_OFF + ((size_t)d * H_ + j) * B_ + b;
    const float c_old = *cp;
    const float c_new = fG * c_old + iG * gG;
    const float h_new = oG * tanhf(c_new);
    const float h_old = hprev[(size_t)j * B_ + b];

    *cp = m ? c_new : c_old;
    ws[HBUF_OFF + ((size_t)((p ^ 1) * 2 + d) * H_ + j) * B_ + b] = m ? h_new : h_old;
    ws[HOUT_OFF + (((size_t)s * 2 + d) * H_ + j) * B_ + b]       = m ? h_new : 0.f;
}

// -------------------- output projection: feats[b][s][t] --------------------
// grid 256 (per s); block 640 = 10 waves (t) x 64 lanes (b)
__global__ __launch_bounds__(640) void k_feats(const float* __restrict__ w_out,
                                               const float* __restrict__ b_out,
                                               float* __restrict__ ws) {
    const int s = blockIdx.x;
    const int t = __builtin_amdgcn_readfirstlane((int)threadIdx.x >> 6);  // 0..9
    const int b = threadIdx.x & 63;
    const float* hs = ws + HOUT_OFF + (size_t)s * (2 * H_) * B_;
    const float* wr = w_out + (size_t)t * (2 * H_);
    float acc = b_out[t];
    for (int j0 = 0; j0 < 2 * H_; j0 += 8) {
        float hv[8];
#pragma unroll
        for (int u = 0; u < 8; u++) hv[u] = hs[(j0 + u) * B_ + b];
#pragma unroll
        for (int u = 0; u < 8; u++) acc += wr[j0 + u] * hv[u];
    }
    ws[FEAT_OFF + ((size_t)b * S_ + s) * T_ + t] = acc;
}

// -------------------- Viterbi decode (one wave per batch row) --------------------
__global__ __launch_bounds__(64) void k_viterbi(const float* __restrict__ start_t,
                                                const float* __restrict__ end_t,
                                                const float* __restrict__ trans,
                                                const int* __restrict__ lengths,
                                                const float* __restrict__ ws,
                                                int* __restrict__ out) {
    const int b = blockIdx.x;
    const int lane = threadIdx.x;
    const int tt = (lane < T_) ? lane : 0;
    const float* feats = ws + FEAT_OFF;
    __shared__ unsigned char bpl[S_][T_];

    float tr[T_];
#pragma unroll
    for (int i = 0; i < T_; i++) tr[i] = trans[i * T_ + tt];   // column tt

    const int len = lengths[b];
    const float* fb = feats + (size_t)b * S_ * T_;
    float score = start_t[tt] + fb[tt];

    for (int s = 1; s < S_; s++) {
        float em = fb[s * T_ + tt];
        float best = -FLT_MAX;
        int bi = 0;
#pragma unroll
        for (int i = 0; i < T_; i++) {
            float si = __shfl(score, i);
            float c = si + tr[i];
            if (c > best) { best = c; bi = i; }   // strict > : first-max like argmax
        }
        bool m = (s < len);
        score = m ? (best + em) : score;
        if (lane < T_) bpl[s][lane] = (unsigned char)(m ? bi : lane);
    }

    float tot = score + end_t[tt];
    float best = -FLT_MAX;
    int last = 0;
#pragma unroll
    for (int i = 0; i < T_; i++) {
        float v = __shfl(tot, i);
        if (v > best) { best = v; last = i; }
    }
    __syncthreads();
    if (lane == 0) {
        int tag = last;
        out[b * S_ + (S_ - 1)] = ((S_ - 1) < len) ? tag : 0;
        for (int s = S_ - 2; s >= 0; s--) {
            tag = bpl[s + 1][tag];
            out[b * S_ + s] = (s < len) ? tag : 0;
        }
    }
}

// -------------------- launcher --------------------
extern "C" void kernel_launch(void* const* d_in, const int* in_sizes, int n_in,
                              void* d_out, int out_size, void* d_ws, size_t ws_size,
                              hipStream_t stream) {
    const int*   tok   = (const int*)  d_in[0];
    const int*   len   = (const int*)  d_in[1];
    const float* emb   = (const float*)d_in[2];
    const float* wih_f = (const float*)d_in[3];
    const float* whh_f = (const float*)d_in[4];
    const float* b_f   = (const float*)d_in[5];
    const float* wih_b = (const float*)d_in[6];
    const float* whh_b = (const float*)d_in[7];
    const float* b_b   = (const float*)d_in[8];
    const float* w_out = (const float*)d_in[9];
    const float* b_out = (const float*)d_in[10];
    const float* st    = (const float*)d_in[11];
    const float* en    = (const float*)d_in[12];
    const float* tr    = (const float*)d_in[13];

    float* ws = (float*)d_ws;
    int* out = (int*)d_out;

    // zero the carried state (ws is poisoned 0xAA before every timed launch)
    hipMemsetAsync(ws + HBUF_OFF, 0, (size_t)(HBUF_SZ + CBUF_SZ) * sizeof(float), stream);

    k_gather<<<2048, 256, 0, stream>>>(tok, emb, ws + X_OFF);

    for (int sIdx = 0; sIdx < S_; sIdx++) {
        k_step<<<256, 256, 0, stream>>>(wih_f, whh_f, b_f, wih_b, whh_b, b_b, len, ws, sIdx);
    }

    k_feats<<<256, 640, 0, stream>>>(w_out, b_out, ws);
    k_viterbi<<<64, 64, 0, stream>>>(st, en, tr, len, ws, out);
}